// Round 1
// baseline (416.519 us; speedup 1.0000x reference)
//
#include <hip/hip_runtime.h>
#include <math.h>

#define N_TOK 32768
#define IN_DIM 1024
#define HID 256
#define NE 64

// ---------------------------------------------------------------------------
// GEMM1: H[N,256] = relu(X[N,1024] @ W1^T[1024,256] + b1)
// grid 512 x 256 threads; block tile = 64 tokens x 256 hidden (full hidden).
// per-thread micro-tile 8 tokens x 8 hidden (64 fp32 accumulators).
// K staged 32 at a time, transposed into LDS as [k][token] / [k][hidden] so
// the inner loop is pure float4 LDS reads + FMA.
// ---------------------------------------------------------------------------
__global__ __launch_bounds__(256, 2)
void gemm1_relu(const float* __restrict__ x, const float* __restrict__ w1,
                const float* __restrict__ b1, float* __restrict__ h)
{
    __shared__ float Xs[32][72];    // [k][token], pad 64->72 (16B-aligned rows)
    __shared__ float Ws[32][256];   // [k][hidden]

    const int tid = threadIdx.x;
    const int t0  = blockIdx.x * 64;
    const int tg  = tid >> 5;       // 0..7   -> tokens  tg*8 .. tg*8+7
    const int hg  = tid & 31;       // 0..31  -> hiddens hg*8 .. hg*8+7

    float acc[8][8];
    #pragma unroll
    for (int i = 0; i < 8; ++i)
        #pragma unroll
        for (int j = 0; j < 8; ++j) acc[i][j] = 0.f;

    for (int k0 = 0; k0 < IN_DIM; k0 += 32) {
        // stage X tile: 64 tok x 32 k = 512 float4, 2 per thread
        #pragma unroll
        for (int r = 0; r < 2; ++r) {
            int slot = tid + 256 * r;
            int t  = slot >> 3;
            int kq = (slot & 7) * 4;
            float4 v = *(const float4*)(x + (size_t)(t0 + t) * IN_DIM + k0 + kq);
            Xs[kq + 0][t] = v.x; Xs[kq + 1][t] = v.y;
            Xs[kq + 2][t] = v.z; Xs[kq + 3][t] = v.w;
        }
        // stage W1 tile: 256 h x 32 k = 2048 float4, 8 per thread
        #pragma unroll
        for (int r = 0; r < 8; ++r) {
            int slot = tid + 256 * r;
            int hh = slot >> 3;
            int kq = (slot & 7) * 4;
            float4 v = *(const float4*)(w1 + (size_t)hh * IN_DIM + k0 + kq);
            Ws[kq + 0][hh] = v.x; Ws[kq + 1][hh] = v.y;
            Ws[kq + 2][hh] = v.z; Ws[kq + 3][hh] = v.w;
        }
        __syncthreads();

        #pragma unroll
        for (int k = 0; k < 32; ++k) {
            float xv[8], wv[8];
            *(float4*)&xv[0] = *(const float4*)&Xs[k][tg * 8];
            *(float4*)&xv[4] = *(const float4*)&Xs[k][tg * 8 + 4];
            *(float4*)&wv[0] = *(const float4*)&Ws[k][hg * 8];
            *(float4*)&wv[4] = *(const float4*)&Ws[k][hg * 8 + 4];
            #pragma unroll
            for (int i = 0; i < 8; ++i)
                #pragma unroll
                for (int j = 0; j < 8; ++j)
                    acc[i][j] = fmaf(xv[i], wv[j], acc[i][j]);
        }
        __syncthreads();
    }

    // epilogue: + bias, relu, coalesced float4 stores
    float4 bv0 = *(const float4*)(b1 + hg * 8);
    float4 bv1 = *(const float4*)(b1 + hg * 8 + 4);
    float bias[8] = {bv0.x, bv0.y, bv0.z, bv0.w, bv1.x, bv1.y, bv1.z, bv1.w};
    #pragma unroll
    for (int i = 0; i < 8; ++i) {
        int t = t0 + tg * 8 + i;
        float4 o0, o1;
        o0.x = fmaxf(acc[i][0] + bias[0], 0.f);
        o0.y = fmaxf(acc[i][1] + bias[1], 0.f);
        o0.z = fmaxf(acc[i][2] + bias[2], 0.f);
        o0.w = fmaxf(acc[i][3] + bias[3], 0.f);
        o1.x = fmaxf(acc[i][4] + bias[4], 0.f);
        o1.y = fmaxf(acc[i][5] + bias[5], 0.f);
        o1.z = fmaxf(acc[i][6] + bias[6], 0.f);
        o1.w = fmaxf(acc[i][7] + bias[7], 0.f);
        *(float4*)(h + (size_t)t * HID + hg * 8)     = o0;
        *(float4*)(h + (size_t)t * HID + hg * 8 + 4) = o1;
    }
}

// ---------------------------------------------------------------------------
// GEMM2 + top-2 + softmax:
// logits[N,64] = H[N,256] @ W2^T[256,64] + b2 ; top-2 by value (ties -> lower
// index, matching jax.lax.top_k), softmax over the 2 kept logits.
// out[0 .. 2N)   = indices (as float, exact)
// out[2N .. 4N)  = gates
// ---------------------------------------------------------------------------
__global__ __launch_bounds__(256, 2)
void gemm2_topk(const float* __restrict__ h, const float* __restrict__ w2,
                const float* __restrict__ b2, float* __restrict__ out)
{
    __shared__ float Hs[32][72];    // [k][token]
    __shared__ float W2s[32][64];   // [k][expert]
    __shared__ float Ls[64][65];    // logits [token][expert], padded

    const int tid = threadIdx.x;
    const int t0  = blockIdx.x * 64;
    const int tg  = tid >> 4;       // 0..15 -> tokens tg*4 .. tg*4+3
    const int eg  = tid & 15;       // 0..15 -> experts eg*4 .. eg*4+3

    float acc[4][4];
    #pragma unroll
    for (int i = 0; i < 4; ++i)
        #pragma unroll
        for (int j = 0; j < 4; ++j) acc[i][j] = 0.f;

    for (int k0 = 0; k0 < HID; k0 += 32) {
        // stage H tile: 64 tok x 32 k = 512 float4, 2 per thread
        #pragma unroll
        for (int r = 0; r < 2; ++r) {
            int slot = tid + 256 * r;
            int t  = slot >> 3;
            int kq = (slot & 7) * 4;
            float4 v = *(const float4*)(h + (size_t)(t0 + t) * HID + k0 + kq);
            Hs[kq + 0][t] = v.x; Hs[kq + 1][t] = v.y;
            Hs[kq + 2][t] = v.z; Hs[kq + 3][t] = v.w;
        }
        // stage W2 tile: 64 e x 32 k = 512 float4, 2 per thread
        #pragma unroll
        for (int r = 0; r < 2; ++r) {
            int slot = tid + 256 * r;
            int e  = slot >> 3;
            int kq = (slot & 7) * 4;
            float4 v = *(const float4*)(w2 + (size_t)e * HID + k0 + kq);
            W2s[kq + 0][e] = v.x; W2s[kq + 1][e] = v.y;
            W2s[kq + 2][e] = v.z; W2s[kq + 3][e] = v.w;
        }
        __syncthreads();

        #pragma unroll
        for (int k = 0; k < 32; ++k) {
            float hv[4], wv[4];
            *(float4*)&hv[0] = *(const float4*)&Hs[k][tg * 4];
            *(float4*)&wv[0] = *(const float4*)&W2s[k][eg * 4];
            #pragma unroll
            for (int i = 0; i < 4; ++i)
                #pragma unroll
                for (int j = 0; j < 4; ++j)
                    acc[i][j] = fmaf(hv[i], wv[j], acc[i][j]);
        }
        __syncthreads();
    }

    // write logits (+bias) to LDS
    float4 b2v = *(const float4*)(b2 + eg * 4);
    float bb[4] = {b2v.x, b2v.y, b2v.z, b2v.w};
    #pragma unroll
    for (int i = 0; i < 4; ++i)
        #pragma unroll
        for (int j = 0; j < 4; ++j)
            Ls[tg * 4 + i][eg * 4 + j] = acc[i][j] + bb[j];
    __syncthreads();

    // one lane per token: top-2 scan (strict > keeps lower index on ties,
    // matching jax.lax.top_k), then 2-way softmax.
    if (tid < 64) {
        const int t = tid;
        float m1 = -INFINITY, m2 = -INFINITY;
        int i1 = 0, i2 = 0;
        #pragma unroll 8
        for (int e = 0; e < NE; ++e) {
            float v = Ls[t][e];
            if (v > m1) { m2 = m1; i2 = i1; m1 = v; i1 = e; }
            else if (v > m2) { m2 = v; i2 = e; }
        }
        float e2  = expf(m2 - m1);           // <= 1, no overflow
        float inv = 1.f / (1.f + e2);
        float g1  = inv;
        float g2  = e2 * inv;
        int gt = t0 + t;
        out[(size_t)gt * 2 + 0] = (float)i1;
        out[(size_t)gt * 2 + 1] = (float)i2;
        out[(size_t)2 * N_TOK + (size_t)gt * 2 + 0] = g1;
        out[(size_t)2 * N_TOK + (size_t)gt * 2 + 1] = g2;
    }
}

extern "C" void kernel_launch(void* const* d_in, const int* in_sizes, int n_in,
                              void* d_out, int out_size, void* d_ws, size_t ws_size,
                              hipStream_t stream) {
    const float* x  = (const float*)d_in[0];  // [32768,1024]
    const float* w1 = (const float*)d_in[1];  // [256,1024]
    const float* b1 = (const float*)d_in[2];  // [256]
    const float* w2 = (const float*)d_in[3];  // [64,256]
    const float* b2 = (const float*)d_in[4];  // [64]
    float* out = (float*)d_out;               // 131072 floats: idx then gates
    float* h   = (float*)d_ws;                // scratch H: 32768*256*4 = 33.6 MB

    gemm1_relu<<<N_TOK / 64, 256, 0, stream>>>(x, w1, b1, h);
    gemm2_topk<<<N_TOK / 64, 256, 0, stream>>>(h, w2, b2, out);
}